// Round 15
// baseline (207.543 us; speedup 1.0000x reference)
//
#include <hip/hip_runtime.h>

#define IN_DIM 128
#define OUT_DIM 128
#define KERN 3
#define NCOL 384          // KERN * IN_DIM
#define BN_EPS 1e-5f
#define SLOPE 0.01f
#define NSHARD 8          // = # XCDs; blockIdx % 8 ~ XCD under round-robin dispatch

typedef unsigned int uint;
typedef unsigned short ushort;
typedef __attribute__((ext_vector_type(8))) short short8;
typedef __attribute__((ext_vector_type(4))) float f32x4;

__device__ __forceinline__ ushort f32_to_bf16(float f) {
    uint b = __float_as_uint(f);
    return (ushort)((b + 0x7fffu + ((b >> 16) & 1u)) >> 16);
}
__device__ __forceinline__ uint pack_bf16x2(float lo, float hi) {
    return (uint)f32_to_bf16(lo) | ((uint)f32_to_bf16(hi) << 16);
}

// ---------------------------------------------------------------------------
// prep: region A zero counts+stats+done, region B h->bf16, region C W permute
// Bt[o][c] = bf16(fc_w[i*384 + k*128 + o]),  c = k*128 + i
// ---------------------------------------------------------------------------
__global__ __launch_bounds__(256) void prep(
    int* __restrict__ zero_base, int nz,
    const float* __restrict__ h, ushort* __restrict__ hb, int total4,
    const float* __restrict__ W, ushort* __restrict__ Bt,
    int gA, int gB)
{
    const int b = blockIdx.x;
    if (b < gA) {
        const int i = b * 256 + threadIdx.x;
        if (i < nz) zero_base[i] = 0;
    } else if (b < gA + gB) {
        const int i = (b - gA) * 256 + threadIdx.x;
        if (i < total4) {
            const float4 v = *(const float4*)&h[(size_t)i * 4];
            ushort4 o;
            o.x = f32_to_bf16(v.x); o.y = f32_to_bf16(v.y);
            o.z = f32_to_bf16(v.z); o.w = f32_to_bf16(v.w);
            *(ushort4*)&hb[(size_t)i * 4] = o;
        }
    } else {
        const int idx = (b - gA - gB) * 256 + threadIdx.x;
        if (idx < 128 * NCOL) {
            const int o = idx / NCOL;
            const int c = idx - o * NCOL;
            const int i = c & 127;
            const int k = c >> 7;
            Bt[idx] = f32_to_bf16(W[(size_t)i * NCOL + (k << 7) + o]);
        }
    }
}

// ---------------------------------------------------------------------------
// 1. histogram of dst
// ---------------------------------------------------------------------------
__global__ __launch_bounds__(256) void hist_dst(
    const int* __restrict__ dst, int* __restrict__ counts, int E)
{
    const int e = blockIdx.x * 256 + threadIdx.x;
    if (e < E) atomicAdd(&counts[dst[e]], 1);
}

// ---------------------------------------------------------------------------
// 2. prefix sum: scan1 per-chunk sums; scan23 = (redundant per-block LDS scan
//    of the <=128 chunk sums) + intra-chunk scan -> row_start AND cursor.
// ---------------------------------------------------------------------------
#define SCHUNK 512

__global__ __launch_bounds__(256) void scan1(
    const int* __restrict__ counts, int* __restrict__ blocksum, int N)
{
    __shared__ int s[256];
    const int tid = threadIdx.x;
    const int base = blockIdx.x * SCHUNK;
    int v = 0;
    if (base + tid < N) v += counts[base + tid];
    if (base + 256 + tid < N) v += counts[base + 256 + tid];
    s[tid] = v;
    __syncthreads();
    for (int off = 128; off > 0; off >>= 1) {
        if (tid < off) s[tid] += s[tid + off];
        __syncthreads();
    }
    if (tid == 0) blocksum[blockIdx.x] = s[0];
}

__global__ __launch_bounds__(512) void scan23(
    const int* __restrict__ counts, const int* __restrict__ blocksum,
    int* __restrict__ row_start, int* __restrict__ cursor,
    int N, int E, int nch)
{
    __shared__ int bs[128];
    __shared__ int s[SCHUNK];
    const int tid = threadIdx.x;

    // redundant per-block inclusive scan of the (<=128) chunk sums
    if (tid < 128) bs[tid] = (tid < nch) ? blocksum[tid] : 0;
    __syncthreads();
    #pragma unroll
    for (int off = 1; off < 128; off <<= 1) {
        int v = 0;
        if (tid < 128 && tid >= off) v = bs[tid - off];
        __syncthreads();
        if (tid < 128) bs[tid] += v;
        __syncthreads();
    }
    const int chunk_excl = (blockIdx.x == 0) ? 0 : bs[blockIdx.x - 1];

    // intra-chunk scan
    const int i = blockIdx.x * SCHUNK + tid;
    const int v0 = (i < N) ? counts[i] : 0;
    s[tid] = v0;
    __syncthreads();
    for (int off = 1; off < SCHUNK; off <<= 1) {
        int t = 0;
        if (tid >= off) t = s[tid - off];
        __syncthreads();
        s[tid] += t;
        __syncthreads();
    }
    if (i < N) {
        const int rs = chunk_excl + s[tid] - v0;
        row_start[i] = rs;
        cursor[i] = rs;
    }
    if (blockIdx.x == 0 && tid == 0) row_start[N] = E;
}

// ---------------------------------------------------------------------------
// 3. per-edge scatter, XCD-SHARDED.  8-byte records: {w0|w1, w2|src<<16}
// ---------------------------------------------------------------------------
__global__ __launch_bounds__(256) void edge_prep(
    const float* __restrict__ pseudo, const int* __restrict__ src,
    const int* __restrict__ dst, const float* __restrict__ mu,
    const float* __restrict__ isg,
    int* __restrict__ cursor, uint2* __restrict__ edata, int E, uint magic)
{
    const int shard = blockIdx.x & (NSHARD - 1);
    const int e = (blockIdx.x >> 3) * 256 + threadIdx.x;
    if (e >= E) return;
    const int d = dst[e];
    int owner = (int)__umulhi((uint)d, magic);
    owner = owner > (NSHARD - 1) ? (NSHARD - 1) : owner;
    if (owner != shard) return;

    const float2 p = *(const float2*)&pseudo[(size_t)e * 2];
    float w[KERN];
    #pragma unroll
    for (int k = 0; k < KERN; ++k) {
        const float dx = (p.x - mu[2 * k])     * isg[2 * k];
        const float dy = (p.y - mu[2 * k + 1]) * isg[2 * k + 1];
        w[k] = __expf(-0.5f * (dx * dx + dy * dy));
    }
    const int pos = atomicAdd(&cursor[d], 1);
    uint2 rec;
    rec.x = pack_bf16x2(w[0], w[1]);
    rec.y = (uint)f32_to_bf16(w[2]) | ((uint)src[e] << 16);
    edata[pos] = rec;
}

// ---------------------------------------------------------------------------
// 4. aggregation (R12-proven, byte-exact): one WAVE per node; two 32-lane
//    halves process two different edges simultaneously (lane loads 8B;
//    32 lanes = 256B row).  Unroll x4 -> 8 rows in flight.  XCD-aligned.
// ---------------------------------------------------------------------------
__global__ __launch_bounds__(256) void edge_aggregate(
    const ushort* __restrict__ hb, const uint2* __restrict__ edata,
    const int* __restrict__ row_start, ushort* __restrict__ g, int N, int sd)
{
    const int s    = blockIdx.x & (NSHARD - 1);
    const int bl   = blockIdx.x >> 3;
    const int wid  = threadIdx.x >> 6;
    const int lane = threadIdx.x & 63;
    const int half = lane >> 5;          // which edge of the pair
    const int l    = lane & 31;          // channel group
    const int dl = bl * 4 + wid;
    if (dl >= sd) return;
    const int d = s * sd + dl;
    if (d >= N) return;

    const int beg = row_start[d];
    const int end = row_start[d + 1];
    const size_t co = (size_t)(l << 2);  // 4 bf16 channels per lane

    float a0[4] = {0.f, 0.f, 0.f, 0.f};
    float a1[4] = {0.f, 0.f, 0.f, 0.f};
    float a2[4] = {0.f, 0.f, 0.f, 0.f};

#define EDGE_ACC(rec, uu)                                                   \
    {                                                                       \
        const float w0 = __uint_as_float((rec).x << 16);                    \
        const float w1 = __uint_as_float((rec).x & 0xffff0000u);            \
        const float w2 = __uint_as_float((rec).y << 16);                    \
        const float v0 = __uint_as_float((uu).x << 16);                     \
        const float v1 = __uint_as_float((uu).x & 0xffff0000u);             \
        const float v2 = __uint_as_float((uu).y << 16);                     \
        const float v3 = __uint_as_float((uu).y & 0xffff0000u);             \
        a0[0] += w0 * v0; a0[1] += w0 * v1; a0[2] += w0 * v2; a0[3] += w0 * v3; \
        a1[0] += w1 * v0; a1[1] += w1 * v1; a1[2] += w1 * v2; a1[3] += w1 * v3; \
        a2[0] += w2 * v0; a2[1] += w2 * v1; a2[2] += w2 * v2; a2[3] += w2 * v3; \
    }

    int i = beg + half;   // half 0: beg, beg+2, ... ; half 1: beg+1, beg+3, ...
    for (; i + 6 < end; i += 8) {
        const uint2 e0 = edata[i];
        const uint2 e1 = edata[i + 2];
        const uint2 e2 = edata[i + 4];
        const uint2 e3 = edata[i + 6];
        const uint2 u0 = *(const uint2*)&hb[(size_t)(e0.y >> 16) * IN_DIM + co];
        const uint2 u1 = *(const uint2*)&hb[(size_t)(e1.y >> 16) * IN_DIM + co];
        const uint2 u2 = *(const uint2*)&hb[(size_t)(e2.y >> 16) * IN_DIM + co];
        const uint2 u3 = *(const uint2*)&hb[(size_t)(e3.y >> 16) * IN_DIM + co];
        EDGE_ACC(e0, u0); EDGE_ACC(e1, u1); EDGE_ACC(e2, u2); EDGE_ACC(e3, u3);
    }
    for (; i < end; i += 2) {
        const uint2 e0 = edata[i];
        const uint2 u0 = *(const uint2*)&hb[(size_t)(e0.y >> 16) * IN_DIM + co];
        EDGE_ACC(e0, u0);
    }
#undef EDGE_ACC

    // combine the two halves (lane l needs lane l+32's partials)
    #pragma unroll
    for (int c = 0; c < 4; ++c) {
        a0[c] += __shfl(a0[c], lane | 32);
        a1[c] += __shfl(a1[c], lane | 32);
        a2[c] += __shfl(a2[c], lane | 32);
    }

    if (half == 0) {
        ushort* gp = g + (size_t)d * NCOL + (l << 2);
        uint2 o0, o1, o2;
        o0.x = pack_bf16x2(a0[0], a0[1]); o0.y = pack_bf16x2(a0[2], a0[3]);
        o1.x = pack_bf16x2(a1[0], a1[1]); o1.y = pack_bf16x2(a1[2], a1[3]);
        o2.x = pack_bf16x2(a2[0], a2[1]); o2.y = pack_bf16x2(a2[2], a2[3]);
        *(uint2*)&gp[0]          = o0;
        *(uint2*)&gp[IN_DIM]     = o1;
        *(uint2*)&gp[2 * IN_DIM] = o2;
    }
}

// ---------------------------------------------------------------------------
// 5. MFMA GEMM + BN stats + MANUAL GRID BARRIER + BN/leaky/residual epilogue.
//    Regular launch (not cooperative).  Co-residency proof: grid = 392 blocks;
//    LDS 33KB -> 4 blocks/CU -> 1024 slots >= 392, so all blocks are resident
//    from dispatch and the spin barrier cannot deadlock.  Early-exit tiles
//    still increment the done counter.  Accumulators never leave registers;
//    Cb and the separate finalize kernel are eliminated.
// ---------------------------------------------------------------------------
#define GBM 128
#define GBK 64

__global__ __launch_bounds__(256) void gemm_bn_fused(
    const ushort* __restrict__ A, const ushort* __restrict__ Bt,
    const ushort* __restrict__ hb, float* __restrict__ out,
    float* __restrict__ stats, int* __restrict__ done,
    const float* __restrict__ gamma, const float* __restrict__ beta,
    int M, int sd, float invN, int nblk)
{
    __shared__ ushort As[GBM * GBK];   // row r at bytes [r*128, ...), swizzled
    __shared__ ushort Bs[128 * GBK];
    __shared__ float sred[256];

    const int sh = blockIdx.x & (NSHARD - 1);
    const int t  = blockIdx.x >> 3;
    const int m0 = sh * sd + t * GBM;
    int rowEnd = sh * sd + sd; if (rowEnd > M) rowEnd = M;
    const int tid = threadIdx.x;

    if (m0 >= rowEnd) {                 // empty tile: still sign the barrier
        if (tid == 0) atomicAdd(done, 1);
        return;
    }

    const int lane = tid & 63;
    const int wid = tid >> 6;
    const int wm = wid >> 1;
    const int wn = wid & 1;

    f32x4 acc[4][4] = {};

    const int lrow = lane & 15;
    const int lk16 = (lane >> 4) * 16;

    for (int k0 = 0; k0 < NCOL; k0 += GBK) {
        #pragma unroll
        for (int p = 0; p < 4; ++p) {
            const int r = (tid >> 3) + p * 32;
            const int s = tid & 7;
            int grow = m0 + r; if (grow >= rowEnd) grow = rowEnd - 1;
            const uint4 v = *(const uint4*)&A[(size_t)grow * NCOL + k0 + s * 8];
            *(uint4*)((char*)As + r * 128 + ((s * 16) ^ ((r & 7) << 4))) = v;
        }
        #pragma unroll
        for (int p = 0; p < 4; ++p) {
            const int r = (tid >> 3) + p * 32;
            const int s = tid & 7;
            const uint4 v = *(const uint4*)&Bt[(size_t)r * NCOL + k0 + s * 8];
            *(uint4*)((char*)Bs + r * 128 + ((s * 16) ^ ((r & 7) << 4))) = v;
        }
        __syncthreads();

        #pragma unroll
        for (int kk = 0; kk < 2; ++kk) {
            short8 af[4], bfr[4];
            #pragma unroll
            for (int i = 0; i < 4; ++i) {
                const int r = wm * 64 + i * 16 + lrow;
                af[i] = *(const short8*)((const char*)As +
                        r * 128 + ((kk * 64 + lk16) ^ ((r & 7) << 4)));
                const int n = wn * 64 + i * 16 + lrow;
                bfr[i] = *(const short8*)((const char*)Bs +
                        n * 128 + ((kk * 64 + lk16) ^ ((n & 7) << 4)));
            }
            #pragma unroll
            for (int i = 0; i < 4; ++i)
                #pragma unroll
                for (int j = 0; j < 4; ++j)
                    acc[i][j] = __builtin_amdgcn_mfma_f32_16x16x32_bf16(
                        af[i], bfr[j], acc[i][j], 0, 0, 0);
        }
        __syncthreads();
    }

    // ---- per-channel stat partials -> global stats ----
    float s[4] = {0.f, 0.f, 0.f, 0.f};
    float ss[4] = {0.f, 0.f, 0.f, 0.f};
    const int rbase = m0 + wm * 64 + (lane >> 4) * 4;
    #pragma unroll
    for (int i = 0; i < 4; ++i) {
        #pragma unroll
        for (int r = 0; r < 4; ++r) {
            const int row = rbase + i * 16 + r;
            if (row < rowEnd) {
                #pragma unroll
                for (int j = 0; j < 4; ++j) {
                    const float v = acc[i][j][r];
                    s[j] += v;
                    ss[j] += v * v;
                }
            }
        }
    }
    sred[tid] = 0.f;
    __syncthreads();
    #pragma unroll
    for (int j = 0; j < 4; ++j) {
        const int col = wn * 64 + j * 16 + lrow;
        atomicAdd(&sred[col], s[j]);
        atomicAdd(&sred[128 + col], ss[j]);
    }
    __syncthreads();
    if (tid < 256) atomicAdd(&stats[tid], sred[tid]);

    // ---- manual grid barrier ----
    __threadfence();
    __syncthreads();
    if (tid == 0) {
        atomicAdd(done, 1);
        while (__hip_atomic_load(done, __ATOMIC_RELAXED,
                                 __HIP_MEMORY_SCOPE_AGENT) < nblk) {
            __builtin_amdgcn_s_sleep(8);
        }
    }
    __syncthreads();

    // ---- epilogue from registers: BN + leaky_relu + residual(hb) ----
    #pragma unroll
    for (int j = 0; j < 4; ++j) {
        const int col = wn * 64 + j * 16 + lrow;
        const float sum = __hip_atomic_load(&stats[col], __ATOMIC_RELAXED,
                                            __HIP_MEMORY_SCOPE_AGENT);
        const float sq  = __hip_atomic_load(&stats[128 + col], __ATOMIC_RELAXED,
                                            __HIP_MEMORY_SCOPE_AGENT);
        const float mean = sum * invN;
        const float var  = sq * invN - mean * mean;
        const float rstd = rsqrtf(var + BN_EPS) * gamma[col];
        const float bet  = beta[col];
        #pragma unroll
        for (int i = 0; i < 4; ++i) {
            #pragma unroll
            for (int r = 0; r < 4; ++r) {
                const int row = rbase + i * 16 + r;
                if (row < rowEnd) {
                    float x = (acc[i][j][r] - mean) * rstd + bet;
                    x = x > 0.f ? x : SLOPE * x;
                    const float hv = __uint_as_float(
                        ((uint)hb[(size_t)row * IN_DIM + col]) << 16);
                    out[(size_t)row * OUT_DIM + col] = x + hv;
                }
            }
        }
    }
}

// ---------------------------------------------------------------------------
extern "C" void kernel_launch(void* const* d_in, const int* in_sizes, int n_in,
                              void* d_out, int out_size, void* d_ws, size_t ws_size,
                              hipStream_t stream)
{
    const float* h      = (const float*)d_in[0];
    const float* pseudo = (const float*)d_in[1];
    const int*   src    = (const int*)d_in[2];
    const int*   dst    = (const int*)d_in[3];
    const float* fc_w   = (const float*)d_in[4];
    const float* mu     = (const float*)d_in[5];
    const float* isg    = (const float*)d_in[6];
    // d_in[7] = bias: cancels exactly inside BatchNorm -> unused
    const float* gamma  = (const float*)d_in[8];
    const float* beta   = (const float*)d_in[9];

    const int N = in_sizes[0] / IN_DIM;   // 50000
    const int E = in_sizes[2];            // 800000

    // workspace layout (~58 MB)
    char* w = (char*)d_ws;
    size_t off = 0;
    uint2*  edata = (uint2*)(w + off);   off += (size_t)E * 8;                  // 6.4 MB
    ushort* g     = (ushort*)(w + off);  off += (size_t)N * NCOL * 2;           // 38.4 MB
    ushort* hb    = (ushort*)(w + off);  off += (size_t)N * IN_DIM * 2;         // 12.8 MB
    ushort* Bt    = (ushort*)(w + off);  off += (size_t)128 * NCOL * 2;         // 96 KB
    off = (off + 255) & ~(size_t)255;
    int* counts    = (int*)(w + off);    off += (size_t)N * 4;
    float* stats   = (float*)(w + off);  off += 256 * 4;
    int* done      = (int*)(w + off);    off += 4;          // counts..done contiguous (zeroed together)
    off = (off + 255) & ~(size_t)255;
    int* row_start = (int*)(w + off);    off += ((size_t)N + 1) * 4;
    off = (off + 255) & ~(size_t)255;
    int* cursor    = (int*)(w + off);    off += (size_t)N * 4;
    off = (off + 255) & ~(size_t)255;
    int* blocksum  = (int*)(w + off);    off += 128 * 4;

    const int nch = (N + SCHUNK - 1) / SCHUNK;   // 98
    const int sd  = (N + NSHARD - 1) / NSHARD;   // 6250 nodes per shard

    // fused prep: zero counts+stats+done | h->bf16 | weight permute
    const int nz = N + 257;
    const int total4 = N * IN_DIM / 4;
    const int gA = (nz + 255) / 256;
    const int gB = (total4 + 255) / 256;
    const int gC = (128 * NCOL + 255) / 256;
    prep<<<gA + gB + gC, 256, 0, stream>>>(counts, nz, h, hb, total4,
                                           fc_w, Bt, gA, gB);

    // CSR build
    hist_dst<<<(E + 255) / 256, 256, 0, stream>>>(dst, counts, E);
    scan1<<<nch, 256, 0, stream>>>(counts, blocksum, N);
    scan23<<<nch, 512, 0, stream>>>(counts, blocksum, row_start, cursor,
                                    N, E, nch);

    // XCD-sharded scatter (8-byte records)
    const uint magic = (uint)(((1ull << 32) + (uint)sd - 1) / (uint)sd);
    const int echunks = (E + 255) / 256;
    edge_prep<<<echunks * NSHARD, 256, 0, stream>>>(pseudo, src, dst, mu, isg,
                                                    cursor, edata, E, magic);

    // aggregation -> g (bf16), XCD-aligned node shards (R12-proven)
    const int ablocks = (sd + 3) / 4;    // blocks per shard
    edge_aggregate<<<ablocks * NSHARD, 256, 0, stream>>>(hb, edata, row_start,
                                                         g, N, sd);

    // fused MFMA GEMM + BN stats + grid barrier + BN/leaky/residual -> d_out
    const int gtiles = (sd + GBM - 1) / GBM;   // tiles per shard
    const int nblk = gtiles * NSHARD;          // 392 blocks, all co-resident
    float* outp = (float*)d_out;
    gemm_bn_fused<<<nblk, 256, 0, stream>>>(g, Bt, hb, outp, stats, done,
                                            gamma, beta, N, sd,
                                            1.0f / (float)N, nblk);
}

// Round 16
// 166.920 us; speedup vs baseline: 1.2434x; 1.2434x over previous
//
#include <hip/hip_runtime.h>

#define IN_DIM 128
#define OUT_DIM 128
#define KERN 3
#define NCOL 384          // KERN * IN_DIM
#define BN_EPS 1e-5f
#define SLOPE 0.01f
#define NSHARD 8          // = # XCDs; blockIdx % 8 ~ XCD under round-robin dispatch

typedef unsigned int uint;
typedef unsigned short ushort;
typedef __attribute__((ext_vector_type(8))) short short8;
typedef __attribute__((ext_vector_type(4))) float f32x4;

__device__ __forceinline__ ushort f32_to_bf16(float f) {
    uint b = __float_as_uint(f);
    return (ushort)((b + 0x7fffu + ((b >> 16) & 1u)) >> 16);
}
__device__ __forceinline__ uint pack_bf16x2(float lo, float hi) {
    return (uint)f32_to_bf16(lo) | ((uint)f32_to_bf16(hi) << 16);
}

// ---------------------------------------------------------------------------
// prep: region A zero counts+stats, region B h->bf16, region C weight permute
// Bt[o][c] = bf16(fc_w[i*384 + k*128 + o]),  c = k*128 + i
// ---------------------------------------------------------------------------
__global__ __launch_bounds__(256) void prep(
    int* __restrict__ zero_base, int nz,
    const float* __restrict__ h, ushort* __restrict__ hb, int total4,
    const float* __restrict__ W, ushort* __restrict__ Bt,
    int gA, int gB)
{
    const int b = blockIdx.x;
    if (b < gA) {
        const int i = b * 256 + threadIdx.x;
        if (i < nz) zero_base[i] = 0;
    } else if (b < gA + gB) {
        const int i = (b - gA) * 256 + threadIdx.x;
        if (i < total4) {
            const float4 v = *(const float4*)&h[(size_t)i * 4];
            ushort4 o;
            o.x = f32_to_bf16(v.x); o.y = f32_to_bf16(v.y);
            o.z = f32_to_bf16(v.z); o.w = f32_to_bf16(v.w);
            *(ushort4*)&hb[(size_t)i * 4] = o;
        }
    } else {
        const int idx = (b - gA - gB) * 256 + threadIdx.x;
        if (idx < 128 * NCOL) {
            const int o = idx / NCOL;
            const int c = idx - o * NCOL;
            const int i = c & 127;
            const int k = c >> 7;
            Bt[idx] = f32_to_bf16(W[(size_t)i * NCOL + (k << 7) + o]);
        }
    }
}

// ---------------------------------------------------------------------------
// 1. histogram of dst
// ---------------------------------------------------------------------------
__global__ __launch_bounds__(256) void hist_dst(
    const int* __restrict__ dst, int* __restrict__ counts, int E)
{
    const int e = blockIdx.x * 256 + threadIdx.x;
    if (e < E) atomicAdd(&counts[dst[e]], 1);
}

// ---------------------------------------------------------------------------
// 2. prefix sum: scan1 per-chunk sums; scan23 = (redundant per-block LDS scan
//    of the <=128 chunk sums) + intra-chunk scan -> row_start AND cursor.
// ---------------------------------------------------------------------------
#define SCHUNK 512

__global__ __launch_bounds__(256) void scan1(
    const int* __restrict__ counts, int* __restrict__ blocksum, int N)
{
    __shared__ int s[256];
    const int tid = threadIdx.x;
    const int base = blockIdx.x * SCHUNK;
    int v = 0;
    if (base + tid < N) v += counts[base + tid];
    if (base + 256 + tid < N) v += counts[base + 256 + tid];
    s[tid] = v;
    __syncthreads();
    for (int off = 128; off > 0; off >>= 1) {
        if (tid < off) s[tid] += s[tid + off];
        __syncthreads();
    }
    if (tid == 0) blocksum[blockIdx.x] = s[0];
}

__global__ __launch_bounds__(512) void scan23(
    const int* __restrict__ counts, const int* __restrict__ blocksum,
    int* __restrict__ row_start, int* __restrict__ cursor,
    int N, int E, int nch)
{
    __shared__ int bs[128];
    __shared__ int s[SCHUNK];
    const int tid = threadIdx.x;

    // redundant per-block inclusive scan of the (<=128) chunk sums
    if (tid < 128) bs[tid] = (tid < nch) ? blocksum[tid] : 0;
    __syncthreads();
    #pragma unroll
    for (int off = 1; off < 128; off <<= 1) {
        int v = 0;
        if (tid < 128 && tid >= off) v = bs[tid - off];
        __syncthreads();
        if (tid < 128) bs[tid] += v;
        __syncthreads();
    }
    const int chunk_excl = (blockIdx.x == 0) ? 0 : bs[blockIdx.x - 1];

    // intra-chunk scan
    const int i = blockIdx.x * SCHUNK + tid;
    const int v0 = (i < N) ? counts[i] : 0;
    s[tid] = v0;
    __syncthreads();
    for (int off = 1; off < SCHUNK; off <<= 1) {
        int t = 0;
        if (tid >= off) t = s[tid - off];
        __syncthreads();
        s[tid] += t;
        __syncthreads();
    }
    if (i < N) {
        const int rs = chunk_excl + s[tid] - v0;
        row_start[i] = rs;
        cursor[i] = rs;
    }
    if (blockIdx.x == 0 && tid == 0) row_start[N] = E;
}

// ---------------------------------------------------------------------------
// 3. per-edge scatter, XCD-SHARDED.  8-byte records: {w0|w1, w2|src<<16}
// ---------------------------------------------------------------------------
__global__ __launch_bounds__(256) void edge_prep(
    const float* __restrict__ pseudo, const int* __restrict__ src,
    const int* __restrict__ dst, const float* __restrict__ mu,
    const float* __restrict__ isg,
    int* __restrict__ cursor, uint2* __restrict__ edata, int E, uint magic)
{
    const int shard = blockIdx.x & (NSHARD - 1);
    const int e = (blockIdx.x >> 3) * 256 + threadIdx.x;
    if (e >= E) return;
    const int d = dst[e];
    int owner = (int)__umulhi((uint)d, magic);
    owner = owner > (NSHARD - 1) ? (NSHARD - 1) : owner;
    if (owner != shard) return;

    const float2 p = *(const float2*)&pseudo[(size_t)e * 2];
    float w[KERN];
    #pragma unroll
    for (int k = 0; k < KERN; ++k) {
        const float dx = (p.x - mu[2 * k])     * isg[2 * k];
        const float dy = (p.y - mu[2 * k + 1]) * isg[2 * k + 1];
        w[k] = __expf(-0.5f * (dx * dx + dy * dy));
    }
    const int pos = atomicAdd(&cursor[d], 1);
    uint2 rec;
    rec.x = pack_bf16x2(w[0], w[1]);
    rec.y = (uint)f32_to_bf16(w[2]) | ((uint)src[e] << 16);
    edata[pos] = rec;
}

// ---------------------------------------------------------------------------
// 4. aggregation (R12-proven lane structure), XCD-ALIGNED node shards.
//    One WAVE per node; two 32-lane halves process two different edges
//    simultaneously (lane loads 8B; 32 lanes = 256B row).  Unroll deepened
//    to x8 -> 16 edge-rows in flight per wave (same instrs/edge, same
//    shuffles; attacks the measured 40% latency-stall fraction).
// ---------------------------------------------------------------------------
__global__ __launch_bounds__(256) void edge_aggregate(
    const ushort* __restrict__ hb, const uint2* __restrict__ edata,
    const int* __restrict__ row_start, ushort* __restrict__ g, int N, int sd)
{
    const int s    = blockIdx.x & (NSHARD - 1);
    const int bl   = blockIdx.x >> 3;
    const int wid  = threadIdx.x >> 6;
    const int lane = threadIdx.x & 63;
    const int half = lane >> 5;          // which edge of the pair
    const int l    = lane & 31;          // channel group
    const int dl = bl * 4 + wid;
    if (dl >= sd) return;
    const int d = s * sd + dl;
    if (d >= N) return;

    const int beg = row_start[d];
    const int end = row_start[d + 1];
    const size_t co = (size_t)(l << 2);  // 4 bf16 channels per lane

    float a0[4] = {0.f, 0.f, 0.f, 0.f};
    float a1[4] = {0.f, 0.f, 0.f, 0.f};
    float a2[4] = {0.f, 0.f, 0.f, 0.f};

#define EDGE_ACC(rec, uu)                                                   \
    {                                                                       \
        const float w0 = __uint_as_float((rec).x << 16);                    \
        const float w1 = __uint_as_float((rec).x & 0xffff0000u);            \
        const float w2 = __uint_as_float((rec).y << 16);                    \
        const float v0 = __uint_as_float((uu).x << 16);                     \
        const float v1 = __uint_as_float((uu).x & 0xffff0000u);             \
        const float v2 = __uint_as_float((uu).y << 16);                     \
        const float v3 = __uint_as_float((uu).y & 0xffff0000u);             \
        a0[0] += w0 * v0; a0[1] += w0 * v1; a0[2] += w0 * v2; a0[3] += w0 * v3; \
        a1[0] += w1 * v0; a1[1] += w1 * v1; a1[2] += w1 * v2; a1[3] += w1 * v3; \
        a2[0] += w2 * v0; a2[1] += w2 * v1; a2[2] += w2 * v2; a2[3] += w2 * v3; \
    }

    int i = beg + half;   // half 0: beg, beg+2, ... ; half 1: beg+1, beg+3, ...
    // 8-deep: 8 record loads + 8 gather loads in flight per half
    for (; i + 14 < end; i += 16) {
        const uint2 e0 = edata[i];
        const uint2 e1 = edata[i + 2];
        const uint2 e2 = edata[i + 4];
        const uint2 e3 = edata[i + 6];
        const uint2 e4 = edata[i + 8];
        const uint2 e5 = edata[i + 10];
        const uint2 e6 = edata[i + 12];
        const uint2 e7 = edata[i + 14];
        const uint2 u0 = *(const uint2*)&hb[(size_t)(e0.y >> 16) * IN_DIM + co];
        const uint2 u1 = *(const uint2*)&hb[(size_t)(e1.y >> 16) * IN_DIM + co];
        const uint2 u2 = *(const uint2*)&hb[(size_t)(e2.y >> 16) * IN_DIM + co];
        const uint2 u3 = *(const uint2*)&hb[(size_t)(e3.y >> 16) * IN_DIM + co];
        const uint2 u4 = *(const uint2*)&hb[(size_t)(e4.y >> 16) * IN_DIM + co];
        const uint2 u5 = *(const uint2*)&hb[(size_t)(e5.y >> 16) * IN_DIM + co];
        const uint2 u6 = *(const uint2*)&hb[(size_t)(e6.y >> 16) * IN_DIM + co];
        const uint2 u7 = *(const uint2*)&hb[(size_t)(e7.y >> 16) * IN_DIM + co];
        EDGE_ACC(e0, u0); EDGE_ACC(e1, u1); EDGE_ACC(e2, u2); EDGE_ACC(e3, u3);
        EDGE_ACC(e4, u4); EDGE_ACC(e5, u5); EDGE_ACC(e6, u6); EDGE_ACC(e7, u7);
    }
    for (; i + 6 < end; i += 8) {
        const uint2 e0 = edata[i];
        const uint2 e1 = edata[i + 2];
        const uint2 e2 = edata[i + 4];
        const uint2 e3 = edata[i + 6];
        const uint2 u0 = *(const uint2*)&hb[(size_t)(e0.y >> 16) * IN_DIM + co];
        const uint2 u1 = *(const uint2*)&hb[(size_t)(e1.y >> 16) * IN_DIM + co];
        const uint2 u2 = *(const uint2*)&hb[(size_t)(e2.y >> 16) * IN_DIM + co];
        const uint2 u3 = *(const uint2*)&hb[(size_t)(e3.y >> 16) * IN_DIM + co];
        EDGE_ACC(e0, u0); EDGE_ACC(e1, u1); EDGE_ACC(e2, u2); EDGE_ACC(e3, u3);
    }
    for (; i < end; i += 2) {
        const uint2 e0 = edata[i];
        const uint2 u0 = *(const uint2*)&hb[(size_t)(e0.y >> 16) * IN_DIM + co];
        EDGE_ACC(e0, u0);
    }
#undef EDGE_ACC

    // combine the two halves (lane l needs lane l+32's partials)
    #pragma unroll
    for (int c = 0; c < 4; ++c) {
        a0[c] += __shfl(a0[c], lane | 32);
        a1[c] += __shfl(a1[c], lane | 32);
        a2[c] += __shfl(a2[c], lane | 32);
    }

    if (half == 0) {
        ushort* gp = g + (size_t)d * NCOL + (l << 2);
        uint2 o0, o1, o2;
        o0.x = pack_bf16x2(a0[0], a0[1]); o0.y = pack_bf16x2(a0[2], a0[3]);
        o1.x = pack_bf16x2(a1[0], a1[1]); o1.y = pack_bf16x2(a1[2], a1[3]);
        o2.x = pack_bf16x2(a2[0], a2[1]); o2.y = pack_bf16x2(a2[2], a2[3]);
        *(uint2*)&gp[0]          = o0;
        *(uint2*)&gp[IN_DIM]     = o1;
        *(uint2*)&gp[2 * IN_DIM] = o2;
    }
}

// ---------------------------------------------------------------------------
// 5. MFMA GEMM, XCD-ALIGNED (R12-proven): 128x128 tile, BK=64, 4 waves,
//    16x16x32 bf16 MFMA, XOR-swizzled LDS.  Fused per-channel BN stats.
// ---------------------------------------------------------------------------
#define GBM 128
#define GBK 64

__global__ __launch_bounds__(256) void gemm_mfma(
    const ushort* __restrict__ A, const ushort* __restrict__ Bt,
    ushort* __restrict__ Cb, float* __restrict__ stats, int M, int sd)
{
    __shared__ ushort As[GBM * GBK];   // row r at bytes [r*128, ...), swizzled
    __shared__ ushort Bs[128 * GBK];
    __shared__ float sred[256];

    const int sh = blockIdx.x & (NSHARD - 1);
    const int t  = blockIdx.x >> 3;
    const int m0 = sh * sd + t * GBM;
    int rowEnd = sh * sd + sd; if (rowEnd > M) rowEnd = M;
    if (m0 >= rowEnd) return;

    const int tid = threadIdx.x;
    const int lane = tid & 63;
    const int wid = tid >> 6;
    const int wm = wid >> 1;
    const int wn = wid & 1;

    f32x4 acc[4][4] = {};

    const int lrow = lane & 15;
    const int lk16 = (lane >> 4) * 16;

    for (int k0 = 0; k0 < NCOL; k0 += GBK) {
        #pragma unroll
        for (int p = 0; p < 4; ++p) {
            const int r = (tid >> 3) + p * 32;
            const int s = tid & 7;
            int grow = m0 + r; if (grow >= rowEnd) grow = rowEnd - 1;
            const uint4 v = *(const uint4*)&A[(size_t)grow * NCOL + k0 + s * 8];
            *(uint4*)((char*)As + r * 128 + ((s * 16) ^ ((r & 7) << 4))) = v;
        }
        #pragma unroll
        for (int p = 0; p < 4; ++p) {
            const int r = (tid >> 3) + p * 32;
            const int s = tid & 7;
            const uint4 v = *(const uint4*)&Bt[(size_t)r * NCOL + k0 + s * 8];
            *(uint4*)((char*)Bs + r * 128 + ((s * 16) ^ ((r & 7) << 4))) = v;
        }
        __syncthreads();

        #pragma unroll
        for (int kk = 0; kk < 2; ++kk) {
            short8 af[4], bfr[4];
            #pragma unroll
            for (int i = 0; i < 4; ++i) {
                const int r = wm * 64 + i * 16 + lrow;
                af[i] = *(const short8*)((const char*)As +
                        r * 128 + ((kk * 64 + lk16) ^ ((r & 7) << 4)));
                const int n = wn * 64 + i * 16 + lrow;
                bfr[i] = *(const short8*)((const char*)Bs +
                        n * 128 + ((kk * 64 + lk16) ^ ((n & 7) << 4)));
            }
            #pragma unroll
            for (int i = 0; i < 4; ++i)
                #pragma unroll
                for (int j = 0; j < 4; ++j)
                    acc[i][j] = __builtin_amdgcn_mfma_f32_16x16x32_bf16(
                        af[i], bfr[j], acc[i][j], 0, 0, 0);
        }
        __syncthreads();
    }

    // epilogue: write Cb (bf16) + per-channel sums/sumsq (from f32 acc)
    float s[4] = {0.f, 0.f, 0.f, 0.f};
    float ss[4] = {0.f, 0.f, 0.f, 0.f};
    const int rbase = m0 + wm * 64 + (lane >> 4) * 4;
    #pragma unroll
    for (int i = 0; i < 4; ++i) {
        #pragma unroll
        for (int r = 0; r < 4; ++r) {
            const int row = rbase + i * 16 + r;
            if (row < rowEnd) {
                #pragma unroll
                for (int j = 0; j < 4; ++j) {
                    const float v = acc[i][j][r];
                    Cb[(size_t)row * OUT_DIM + wn * 64 + j * 16 + lrow] =
                        f32_to_bf16(v);
                    s[j] += v;
                    ss[j] += v * v;
                }
            }
        }
    }
    sred[tid] = 0.f;
    __syncthreads();
    #pragma unroll
    for (int j = 0; j < 4; ++j) {
        const int col = wn * 64 + j * 16 + lrow;
        atomicAdd(&sred[col], s[j]);
        atomicAdd(&sred[128 + col], ss[j]);
    }
    __syncthreads();
    if (tid < 256) atomicAdd(&stats[tid], sred[tid]);
}

// ---------------------------------------------------------------------------
// 6. finalize, XCD-ALIGNED: BN + leaky_relu + residual(hb).  Reads bf16 C.
// ---------------------------------------------------------------------------
__global__ __launch_bounds__(256) void finalize(
    const ushort* __restrict__ Cb, const ushort* __restrict__ hb,
    float* __restrict__ out,
    const float* __restrict__ stats, const float* __restrict__ gamma,
    const float* __restrict__ beta, int qd, int total, float invN)
{
    const int s = blockIdx.x & (NSHARD - 1);
    const int il = (blockIdx.x >> 3) * 256 + threadIdx.x;
    if (il >= qd) return;
    const int i4 = s * (qd << 2) + il * 4;
    if (i4 >= total) return;
    const int o4 = i4 & 127;

    const uint2 cu = *(const uint2*)&Cb[i4];
    const uint2 hu = *(const uint2*)&hb[i4];
    float r[4], hv[4];
    r[0] = __uint_as_float(cu.x << 16); r[1] = __uint_as_float(cu.x & 0xffff0000u);
    r[2] = __uint_as_float(cu.y << 16); r[3] = __uint_as_float(cu.y & 0xffff0000u);
    hv[0] = __uint_as_float(hu.x << 16); hv[1] = __uint_as_float(hu.x & 0xffff0000u);
    hv[2] = __uint_as_float(hu.y << 16); hv[3] = __uint_as_float(hu.y & 0xffff0000u);

    float res[4];
    #pragma unroll
    for (int j = 0; j < 4; ++j) {
        const int o = o4 + j;
        const float mean = stats[o] * invN;
        const float var = stats[128 + o] * invN - mean * mean;
        float x = (r[j] - mean) * rsqrtf(var + BN_EPS) * gamma[o] + beta[o];
        x = x > 0.f ? x : SLOPE * x;
        res[j] = x + hv[j];
    }
    *(float4*)&out[i4] = make_float4(res[0], res[1], res[2], res[3]);
}

// ---------------------------------------------------------------------------
extern "C" void kernel_launch(void* const* d_in, const int* in_sizes, int n_in,
                              void* d_out, int out_size, void* d_ws, size_t ws_size,
                              hipStream_t stream)
{
    const float* h      = (const float*)d_in[0];
    const float* pseudo = (const float*)d_in[1];
    const int*   src    = (const int*)d_in[2];
    const int*   dst    = (const int*)d_in[3];
    const float* fc_w   = (const float*)d_in[4];
    const float* mu     = (const float*)d_in[5];
    const float* isg    = (const float*)d_in[6];
    // d_in[7] = bias: cancels exactly inside BatchNorm -> unused
    const float* gamma  = (const float*)d_in[8];
    const float* beta   = (const float*)d_in[9];

    const int N = in_sizes[0] / IN_DIM;   // 50000
    const int E = in_sizes[2];            // 800000

    // workspace layout (~71 MB)
    char* w = (char*)d_ws;
    size_t off = 0;
    uint2*  edata = (uint2*)(w + off);   off += (size_t)E * 8;                  // 6.4 MB
    ushort* g     = (ushort*)(w + off);  off += (size_t)N * NCOL * 2;           // 38.4 MB
    ushort* hb    = (ushort*)(w + off);  off += (size_t)N * IN_DIM * 2;         // 12.8 MB
    ushort* Cb    = (ushort*)(w + off);  off += (size_t)N * OUT_DIM * 2;        // 12.8 MB
    ushort* Bt    = (ushort*)(w + off);  off += (size_t)128 * NCOL * 2;         // 96 KB
    off = (off + 255) & ~(size_t)255;
    int* counts    = (int*)(w + off);    off += (size_t)N * 4;
    float* stats   = (float*)(w + off);  off += 256 * 4;   // counts..stats contiguous (zeroed together)
    off = (off + 255) & ~(size_t)255;
    int* row_start = (int*)(w + off);    off += ((size_t)N + 1) * 4;
    off = (off + 255) & ~(size_t)255;
    int* cursor    = (int*)(w + off);    off += (size_t)N * 4;
    off = (off + 255) & ~(size_t)255;
    int* blocksum  = (int*)(w + off);    off += 128 * 4;

    const int nch = (N + SCHUNK - 1) / SCHUNK;   // 98
    const int sd  = (N + NSHARD - 1) / NSHARD;   // 6250 nodes per shard

    // fused prep: zero counts+stats | h->bf16 | weight permute
    const int nz = N + 256;
    const int total4 = N * IN_DIM / 4;
    const int gA = (nz + 255) / 256;
    const int gB = (total4 + 255) / 256;
    const int gC = (128 * NCOL + 255) / 256;
    prep<<<gA + gB + gC, 256, 0, stream>>>(counts, nz, h, hb, total4,
                                           fc_w, Bt, gA, gB);

    // CSR build (scan2 merged into scan23)
    hist_dst<<<(E + 255) / 256, 256, 0, stream>>>(dst, counts, E);
    scan1<<<nch, 256, 0, stream>>>(counts, blocksum, N);
    scan23<<<nch, 512, 0, stream>>>(counts, blocksum, row_start, cursor,
                                    N, E, nch);

    // XCD-sharded scatter (8-byte records)
    const uint magic = (uint)(((1ull << 32) + (uint)sd - 1) / (uint)sd);
    const int echunks = (E + 255) / 256;
    edge_prep<<<echunks * NSHARD, 256, 0, stream>>>(pseudo, src, dst, mu, isg,
                                                    cursor, edata, E, magic);

    // aggregation -> g (bf16), XCD-aligned node shards, 8-deep unroll
    const int ablocks = (sd + 3) / 4;    // blocks per shard
    edge_aggregate<<<ablocks * NSHARD, 256, 0, stream>>>(hb, edata, row_start,
                                                         g, N, sd);

    // MFMA GEMM -> Cb (bf16), fused BN stats, XCD-aligned
    const int gtiles = (sd + GBM - 1) / GBM;   // tiles per shard
    gemm_mfma<<<gtiles * NSHARD, 256, 0, stream>>>(g, Bt, Cb, stats, N, sd);

    // BN + leaky_relu + residual -> d_out, XCD-aligned
    const int qd = sd * (OUT_DIM / 4);         // f32x4-quads per shard
    const int fblocks = (qd + 255) / 256;
    float* outp = (float*)d_out;
    finalize<<<fblocks * NSHARD, 256, 0, stream>>>(
        Cb, hb, outp, stats, gamma, beta, qd, N * OUT_DIM, 1.0f / (float)N);
}

// Round 17
// 164.047 us; speedup vs baseline: 1.2651x; 1.0175x over previous
//
#include <hip/hip_runtime.h>

#define IN_DIM 128
#define OUT_DIM 128
#define KERN 3
#define NCOL 384          // KERN * IN_DIM
#define BN_EPS 1e-5f
#define SLOPE 0.01f
#define NSHARD 8          // = # XCDs; blockIdx % 8 ~ XCD under round-robin dispatch

typedef unsigned int uint;
typedef unsigned short ushort;
typedef __attribute__((ext_vector_type(8))) short short8;
typedef __attribute__((ext_vector_type(4))) float f32x4;

__device__ __forceinline__ ushort f32_to_bf16(float f) {
    uint b = __float_as_uint(f);
    return (ushort)((b + 0x7fffu + ((b >> 16) & 1u)) >> 16);
}
__device__ __forceinline__ uint pack_bf16x2(float lo, float hi) {
    return (uint)f32_to_bf16(lo) | ((uint)f32_to_bf16(hi) << 16);
}

// ---------------------------------------------------------------------------
// prep: region A zero counts+stats, region B h->bf16, region C weight permute
// Bt[o][c] = bf16(fc_w[i*384 + k*128 + o]),  c = k*128 + i
// ---------------------------------------------------------------------------
__global__ __launch_bounds__(256) void prep(
    int* __restrict__ zero_base, int nz,
    const float* __restrict__ h, ushort* __restrict__ hb, int total4,
    const float* __restrict__ W, ushort* __restrict__ Bt,
    int gA, int gB)
{
    const int b = blockIdx.x;
    if (b < gA) {
        const int i = b * 256 + threadIdx.x;
        if (i < nz) zero_base[i] = 0;
    } else if (b < gA + gB) {
        const int i = (b - gA) * 256 + threadIdx.x;
        if (i < total4) {
            const float4 v = *(const float4*)&h[(size_t)i * 4];
            ushort4 o;
            o.x = f32_to_bf16(v.x); o.y = f32_to_bf16(v.y);
            o.z = f32_to_bf16(v.z); o.w = f32_to_bf16(v.w);
            *(ushort4*)&hb[(size_t)i * 4] = o;
        }
    } else {
        const int idx = (b - gA - gB) * 256 + threadIdx.x;
        if (idx < 128 * NCOL) {
            const int o = idx / NCOL;
            const int c = idx - o * NCOL;
            const int i = c & 127;
            const int k = c >> 7;
            Bt[idx] = f32_to_bf16(W[(size_t)i * NCOL + (k << 7) + o]);
        }
    }
}

// ---------------------------------------------------------------------------
// 1. histogram of dst
// ---------------------------------------------------------------------------
__global__ __launch_bounds__(256) void hist_dst(
    const int* __restrict__ dst, int* __restrict__ counts, int E)
{
    const int e = blockIdx.x * 256 + threadIdx.x;
    if (e < E) atomicAdd(&counts[dst[e]], 1);
}

// ---------------------------------------------------------------------------
// 2. prefix sum: scan1 per-chunk sums; scan23 = (redundant per-block LDS scan
//    of the <=128 chunk sums) + intra-chunk scan -> row_start AND cursor.
// ---------------------------------------------------------------------------
#define SCHUNK 512

__global__ __launch_bounds__(256) void scan1(
    const int* __restrict__ counts, int* __restrict__ blocksum, int N)
{
    __shared__ int s[256];
    const int tid = threadIdx.x;
    const int base = blockIdx.x * SCHUNK;
    int v = 0;
    if (base + tid < N) v += counts[base + tid];
    if (base + 256 + tid < N) v += counts[base + 256 + tid];
    s[tid] = v;
    __syncthreads();
    for (int off = 128; off > 0; off >>= 1) {
        if (tid < off) s[tid] += s[tid + off];
        __syncthreads();
    }
    if (tid == 0) blocksum[blockIdx.x] = s[0];
}

__global__ __launch_bounds__(512) void scan23(
    const int* __restrict__ counts, const int* __restrict__ blocksum,
    int* __restrict__ row_start, int* __restrict__ cursor,
    int N, int E, int nch)
{
    __shared__ int bs[128];
    __shared__ int s[SCHUNK];
    const int tid = threadIdx.x;

    // redundant per-block inclusive scan of the (<=128) chunk sums
    if (tid < 128) bs[tid] = (tid < nch) ? blocksum[tid] : 0;
    __syncthreads();
    #pragma unroll
    for (int off = 1; off < 128; off <<= 1) {
        int v = 0;
        if (tid < 128 && tid >= off) v = bs[tid - off];
        __syncthreads();
        if (tid < 128) bs[tid] += v;
        __syncthreads();
    }
    const int chunk_excl = (blockIdx.x == 0) ? 0 : bs[blockIdx.x - 1];

    // intra-chunk scan
    const int i = blockIdx.x * SCHUNK + tid;
    const int v0 = (i < N) ? counts[i] : 0;
    s[tid] = v0;
    __syncthreads();
    for (int off = 1; off < SCHUNK; off <<= 1) {
        int t = 0;
        if (tid >= off) t = s[tid - off];
        __syncthreads();
        s[tid] += t;
        __syncthreads();
    }
    if (i < N) {
        const int rs = chunk_excl + s[tid] - v0;
        row_start[i] = rs;
        cursor[i] = rs;
    }
    if (blockIdx.x == 0 && tid == 0) row_start[N] = E;
}

// ---------------------------------------------------------------------------
// 3. per-edge scatter, XCD-SHARDED.  8-byte records: {w0|w1, w2|src<<16}
// ---------------------------------------------------------------------------
__global__ __launch_bounds__(256) void edge_prep(
    const float* __restrict__ pseudo, const int* __restrict__ src,
    const int* __restrict__ dst, const float* __restrict__ mu,
    const float* __restrict__ isg,
    int* __restrict__ cursor, uint2* __restrict__ edata, int E, uint magic)
{
    const int shard = blockIdx.x & (NSHARD - 1);
    const int e = (blockIdx.x >> 3) * 256 + threadIdx.x;
    if (e >= E) return;
    const int d = dst[e];
    int owner = (int)__umulhi((uint)d, magic);
    owner = owner > (NSHARD - 1) ? (NSHARD - 1) : owner;
    if (owner != shard) return;

    const float2 p = *(const float2*)&pseudo[(size_t)e * 2];
    float w[KERN];
    #pragma unroll
    for (int k = 0; k < KERN; ++k) {
        const float dx = (p.x - mu[2 * k])     * isg[2 * k];
        const float dy = (p.y - mu[2 * k + 1]) * isg[2 * k + 1];
        w[k] = __expf(-0.5f * (dx * dx + dy * dy));
    }
    const int pos = atomicAdd(&cursor[d], 1);
    uint2 rec;
    rec.x = pack_bf16x2(w[0], w[1]);
    rec.y = (uint)f32_to_bf16(w[2]) | ((uint)src[e] << 16);
    edata[pos] = rec;
}

// ---------------------------------------------------------------------------
// 4. aggregation (R12-proven, byte-exact): one WAVE per node; two 32-lane
//    halves process two different edges simultaneously (lane loads 8B;
//    32 lanes = 256B row).  Unroll x4 -> 8 rows in flight.  XCD-aligned.
// ---------------------------------------------------------------------------
__global__ __launch_bounds__(256) void edge_aggregate(
    const ushort* __restrict__ hb, const uint2* __restrict__ edata,
    const int* __restrict__ row_start, ushort* __restrict__ g, int N, int sd)
{
    const int s    = blockIdx.x & (NSHARD - 1);
    const int bl   = blockIdx.x >> 3;
    const int wid  = threadIdx.x >> 6;
    const int lane = threadIdx.x & 63;
    const int half = lane >> 5;          // which edge of the pair
    const int l    = lane & 31;          // channel group
    const int dl = bl * 4 + wid;
    if (dl >= sd) return;
    const int d = s * sd + dl;
    if (d >= N) return;

    const int beg = row_start[d];
    const int end = row_start[d + 1];
    const size_t co = (size_t)(l << 2);  // 4 bf16 channels per lane

    float a0[4] = {0.f, 0.f, 0.f, 0.f};
    float a1[4] = {0.f, 0.f, 0.f, 0.f};
    float a2[4] = {0.f, 0.f, 0.f, 0.f};

#define EDGE_ACC(rec, uu)                                                   \
    {                                                                       \
        const float w0 = __uint_as_float((rec).x << 16);                    \
        const float w1 = __uint_as_float((rec).x & 0xffff0000u);            \
        const float w2 = __uint_as_float((rec).y << 16);                    \
        const float v0 = __uint_as_float((uu).x << 16);                     \
        const float v1 = __uint_as_float((uu).x & 0xffff0000u);             \
        const float v2 = __uint_as_float((uu).y << 16);                     \
        const float v3 = __uint_as_float((uu).y & 0xffff0000u);             \
        a0[0] += w0 * v0; a0[1] += w0 * v1; a0[2] += w0 * v2; a0[3] += w0 * v3; \
        a1[0] += w1 * v0; a1[1] += w1 * v1; a1[2] += w1 * v2; a1[3] += w1 * v3; \
        a2[0] += w2 * v0; a2[1] += w2 * v1; a2[2] += w2 * v2; a2[3] += w2 * v3; \
    }

    int i = beg + half;   // half 0: beg, beg+2, ... ; half 1: beg+1, beg+3, ...
    for (; i + 6 < end; i += 8) {
        const uint2 e0 = edata[i];
        const uint2 e1 = edata[i + 2];
        const uint2 e2 = edata[i + 4];
        const uint2 e3 = edata[i + 6];
        const uint2 u0 = *(const uint2*)&hb[(size_t)(e0.y >> 16) * IN_DIM + co];
        const uint2 u1 = *(const uint2*)&hb[(size_t)(e1.y >> 16) * IN_DIM + co];
        const uint2 u2 = *(const uint2*)&hb[(size_t)(e2.y >> 16) * IN_DIM + co];
        const uint2 u3 = *(const uint2*)&hb[(size_t)(e3.y >> 16) * IN_DIM + co];
        EDGE_ACC(e0, u0); EDGE_ACC(e1, u1); EDGE_ACC(e2, u2); EDGE_ACC(e3, u3);
    }
    for (; i < end; i += 2) {
        const uint2 e0 = edata[i];
        const uint2 u0 = *(const uint2*)&hb[(size_t)(e0.y >> 16) * IN_DIM + co];
        EDGE_ACC(e0, u0);
    }
#undef EDGE_ACC

    // combine the two halves (lane l needs lane l+32's partials)
    #pragma unroll
    for (int c = 0; c < 4; ++c) {
        a0[c] += __shfl(a0[c], lane | 32);
        a1[c] += __shfl(a1[c], lane | 32);
        a2[c] += __shfl(a2[c], lane | 32);
    }

    if (half == 0) {
        ushort* gp = g + (size_t)d * NCOL + (l << 2);
        uint2 o0, o1, o2;
        o0.x = pack_bf16x2(a0[0], a0[1]); o0.y = pack_bf16x2(a0[2], a0[3]);
        o1.x = pack_bf16x2(a1[0], a1[1]); o1.y = pack_bf16x2(a1[2], a1[3]);
        o2.x = pack_bf16x2(a2[0], a2[1]); o2.y = pack_bf16x2(a2[2], a2[3]);
        *(uint2*)&gp[0]          = o0;
        *(uint2*)&gp[IN_DIM]     = o1;
        *(uint2*)&gp[2 * IN_DIM] = o2;
    }
}

// ---------------------------------------------------------------------------
// 5. MFMA GEMM, XCD-ALIGNED (R12-proven): 128x128 tile, BK=64, 4 waves,
//    16x16x32 bf16 MFMA, XOR-swizzled LDS.  Fused per-channel BN stats.
// ---------------------------------------------------------------------------
#define GBM 128
#define GBK 64

__global__ __launch_bounds__(256) void gemm_mfma(
    const ushort* __restrict__ A, const ushort* __restrict__ Bt,
    ushort* __restrict__ Cb, float* __restrict__ stats, int M, int sd)
{
    __shared__ ushort As[GBM * GBK];   // row r at bytes [r*128, ...), swizzled
    __shared__ ushort Bs[128 * GBK];
    __shared__ float sred[256];

    const int sh = blockIdx.x & (NSHARD - 1);
    const int t  = blockIdx.x >> 3;
    const int m0 = sh * sd + t * GBM;
    int rowEnd = sh * sd + sd; if (rowEnd > M) rowEnd = M;
    if (m0 >= rowEnd) return;

    const int tid = threadIdx.x;
    const int lane = tid & 63;
    const int wid = tid >> 6;
    const int wm = wid >> 1;
    const int wn = wid & 1;

    f32x4 acc[4][4] = {};

    const int lrow = lane & 15;
    const int lk16 = (lane >> 4) * 16;

    for (int k0 = 0; k0 < NCOL; k0 += GBK) {
        #pragma unroll
        for (int p = 0; p < 4; ++p) {
            const int r = (tid >> 3) + p * 32;
            const int s = tid & 7;
            int grow = m0 + r; if (grow >= rowEnd) grow = rowEnd - 1;
            const uint4 v = *(const uint4*)&A[(size_t)grow * NCOL + k0 + s * 8];
            *(uint4*)((char*)As + r * 128 + ((s * 16) ^ ((r & 7) << 4))) = v;
        }
        #pragma unroll
        for (int p = 0; p < 4; ++p) {
            const int r = (tid >> 3) + p * 32;
            const int s = tid & 7;
            const uint4 v = *(const uint4*)&Bt[(size_t)r * NCOL + k0 + s * 8];
            *(uint4*)((char*)Bs + r * 128 + ((s * 16) ^ ((r & 7) << 4))) = v;
        }
        __syncthreads();

        #pragma unroll
        for (int kk = 0; kk < 2; ++kk) {
            short8 af[4], bfr[4];
            #pragma unroll
            for (int i = 0; i < 4; ++i) {
                const int r = wm * 64 + i * 16 + lrow;
                af[i] = *(const short8*)((const char*)As +
                        r * 128 + ((kk * 64 + lk16) ^ ((r & 7) << 4)));
                const int n = wn * 64 + i * 16 + lrow;
                bfr[i] = *(const short8*)((const char*)Bs +
                        n * 128 + ((kk * 64 + lk16) ^ ((n & 7) << 4)));
            }
            #pragma unroll
            for (int i = 0; i < 4; ++i)
                #pragma unroll
                for (int j = 0; j < 4; ++j)
                    acc[i][j] = __builtin_amdgcn_mfma_f32_16x16x32_bf16(
                        af[i], bfr[j], acc[i][j], 0, 0, 0);
        }
        __syncthreads();
    }

    // epilogue: write Cb (bf16) + per-channel sums/sumsq (from f32 acc)
    float s[4] = {0.f, 0.f, 0.f, 0.f};
    float ss[4] = {0.f, 0.f, 0.f, 0.f};
    const int rbase = m0 + wm * 64 + (lane >> 4) * 4;
    #pragma unroll
    for (int i = 0; i < 4; ++i) {
        #pragma unroll
        for (int r = 0; r < 4; ++r) {
            const int row = rbase + i * 16 + r;
            if (row < rowEnd) {
                #pragma unroll
                for (int j = 0; j < 4; ++j) {
                    const float v = acc[i][j][r];
                    Cb[(size_t)row * OUT_DIM + wn * 64 + j * 16 + lrow] =
                        f32_to_bf16(v);
                    s[j] += v;
                    ss[j] += v * v;
                }
            }
        }
    }
    sred[tid] = 0.f;
    __syncthreads();
    #pragma unroll
    for (int j = 0; j < 4; ++j) {
        const int col = wn * 64 + j * 16 + lrow;
        atomicAdd(&sred[col], s[j]);
        atomicAdd(&sred[128 + col], ss[j]);
    }
    __syncthreads();
    if (tid < 256) atomicAdd(&stats[tid], sred[tid]);
}

// ---------------------------------------------------------------------------
// 6. finalize, XCD-ALIGNED: BN + leaky_relu + residual(hb).  Reads bf16 C.
// ---------------------------------------------------------------------------
__global__ __launch_bounds__(256) void finalize(
    const ushort* __restrict__ Cb, const ushort* __restrict__ hb,
    float* __restrict__ out,
    const float* __restrict__ stats, const float* __restrict__ gamma,
    const float* __restrict__ beta, int qd, int total, float invN)
{
    const int s = blockIdx.x & (NSHARD - 1);
    const int il = (blockIdx.x >> 3) * 256 + threadIdx.x;
    if (il >= qd) return;
    const int i4 = s * (qd << 2) + il * 4;
    if (i4 >= total) return;
    const int o4 = i4 & 127;

    const uint2 cu = *(const uint2*)&Cb[i4];
    const uint2 hu = *(const uint2*)&hb[i4];
    float r[4], hv[4];
    r[0] = __uint_as_float(cu.x << 16); r[1] = __uint_as_float(cu.x & 0xffff0000u);
    r[2] = __uint_as_float(cu.y << 16); r[3] = __uint_as_float(cu.y & 0xffff0000u);
    hv[0] = __uint_as_float(hu.x << 16); hv[1] = __uint_as_float(hu.x & 0xffff0000u);
    hv[2] = __uint_as_float(hu.y << 16); hv[3] = __uint_as_float(hu.y & 0xffff0000u);

    float res[4];
    #pragma unroll
    for (int j = 0; j < 4; ++j) {
        const int o = o4 + j;
        const float mean = stats[o] * invN;
        const float var = stats[128 + o] * invN - mean * mean;
        float x = (r[j] - mean) * rsqrtf(var + BN_EPS) * gamma[o] + beta[o];
        x = x > 0.f ? x : SLOPE * x;
        res[j] = x + hv[j];
    }
    *(float4*)&out[i4] = make_float4(res[0], res[1], res[2], res[3]);
}

// ---------------------------------------------------------------------------
extern "C" void kernel_launch(void* const* d_in, const int* in_sizes, int n_in,
                              void* d_out, int out_size, void* d_ws, size_t ws_size,
                              hipStream_t stream)
{
    const float* h      = (const float*)d_in[0];
    const float* pseudo = (const float*)d_in[1];
    const int*   src    = (const int*)d_in[2];
    const int*   dst    = (const int*)d_in[3];
    const float* fc_w   = (const float*)d_in[4];
    const float* mu     = (const float*)d_in[5];
    const float* isg    = (const float*)d_in[6];
    // d_in[7] = bias: cancels exactly inside BatchNorm -> unused
    const float* gamma  = (const float*)d_in[8];
    const float* beta   = (const float*)d_in[9];

    const int N = in_sizes[0] / IN_DIM;   // 50000
    const int E = in_sizes[2];            // 800000

    // workspace layout (~71 MB)
    char* w = (char*)d_ws;
    size_t off = 0;
    uint2*  edata = (uint2*)(w + off);   off += (size_t)E * 8;                  // 6.4 MB
    ushort* g     = (ushort*)(w + off);  off += (size_t)N * NCOL * 2;           // 38.4 MB
    ushort* hb    = (ushort*)(w + off);  off += (size_t)N * IN_DIM * 2;         // 12.8 MB
    ushort* Cb    = (ushort*)(w + off);  off += (size_t)N * OUT_DIM * 2;        // 12.8 MB
    ushort* Bt    = (ushort*)(w + off);  off += (size_t)128 * NCOL * 2;         // 96 KB
    off = (off + 255) & ~(size_t)255;
    int* counts    = (int*)(w + off);    off += (size_t)N * 4;
    float* stats   = (float*)(w + off);  off += 256 * 4;   // counts..stats contiguous (zeroed together)
    off = (off + 255) & ~(size_t)255;
    int* row_start = (int*)(w + off);    off += ((size_t)N + 1) * 4;
    off = (off + 255) & ~(size_t)255;
    int* cursor    = (int*)(w + off);    off += (size_t)N * 4;
    off = (off + 255) & ~(size_t)255;
    int* blocksum  = (int*)(w + off);    off += 128 * 4;

    const int nch = (N + SCHUNK - 1) / SCHUNK;   // 98
    const int sd  = (N + NSHARD - 1) / NSHARD;   // 6250 nodes per shard

    // fused prep: zero counts+stats | h->bf16 | weight permute
    const int nz = N + 256;
    const int total4 = N * IN_DIM / 4;
    const int gA = (nz + 255) / 256;
    const int gB = (total4 + 255) / 256;
    const int gC = (128 * NCOL + 255) / 256;
    prep<<<gA + gB + gC, 256, 0, stream>>>(counts, nz, h, hb, total4,
                                           fc_w, Bt, gA, gB);

    // CSR build (scan2 merged into scan23)
    hist_dst<<<(E + 255) / 256, 256, 0, stream>>>(dst, counts, E);
    scan1<<<nch, 256, 0, stream>>>(counts, blocksum, N);
    scan23<<<nch, 512, 0, stream>>>(counts, blocksum, row_start, cursor,
                                    N, E, nch);

    // XCD-sharded scatter (8-byte records)
    const uint magic = (uint)(((1ull << 32) + (uint)sd - 1) / (uint)sd);
    const int echunks = (E + 255) / 256;
    edge_prep<<<echunks * NSHARD, 256, 0, stream>>>(pseudo, src, dst, mu, isg,
                                                    cursor, edata, E, magic);

    // aggregation -> g (bf16), XCD-aligned node shards (R12-proven 4-deep)
    const int ablocks = (sd + 3) / 4;    // blocks per shard
    edge_aggregate<<<ablocks * NSHARD, 256, 0, stream>>>(hb, edata, row_start,
                                                         g, N, sd);

    // MFMA GEMM -> Cb (bf16), fused BN stats, XCD-aligned
    const int gtiles = (sd + GBM - 1) / GBM;   // tiles per shard
    gemm_mfma<<<gtiles * NSHARD, 256, 0, stream>>>(g, Bt, Cb, stats, N, sd);

    // BN + leaky_relu + residual -> d_out, XCD-aligned
    const int qd = sd * (OUT_DIM / 4);         // f32x4-quads per shard
    const int fblocks = (qd + 255) / 256;
    float* outp = (float*)d_out;
    finalize<<<fblocks * NSHARD, 256, 0, stream>>>(
        Cb, hb, outp, stats, gamma, beta, qd, N * OUT_DIM, 1.0f / (float)N);
}